// Round 1
// baseline (103.631 us; speedup 1.0000x reference)
//
#include <hip/hip_runtime.h>
#include <math.h>

// HeteAttention capsule routing, MI355X.
// Shapes (hard-coded per reference setup): B=4096, n=1, N=128 neighbors,
// F=8 facets, D=16 emb_dim, n_iter=4. C = F*D = 128.
// One block of 256 threads per batch element b. z[b] (128x128 f32 = 64KB)
// is staged+L2-normalized into LDS once, then reused for all 4 routing iters.

#define DD 16
#define FF 8
#define NNB 128
#define CC 128           // FF*DD
#define ZSTRIDE 132      // 128 + 4 pad: keeps float4 alignment, spreads banks
#define PSTRIDE 9        // odd stride -> conflict-free over k

__global__ __launch_bounds__(256, 2)
void hete_routing_kernel(const float* __restrict__ feat,   // [B, 128]
                         const float* __restrict__ mp,     // [B, 128, 128]
                         float* __restrict__ out)          // [B, 128]
{
    // LDS carve-out: 16896 (z) + 1152 (w) + 1152 (p/part alias) + 128 + 128
    __shared__ float smem[16896 + 1152 + 1152 + 128 + 128];
    float* z_s    = smem;                  // [128][132] normalized z
    float* w_s    = z_s + 16896;           // [128][9]   softmax weights
    float* p_s    = w_s + 1152;            // [128][9]   logits
    float* part_s = p_s;                   // [8][128]   aliases p_s (logits dead)
    float* u_s    = p_s + 1152;            // [128]
    float* x_s    = u_s + 128;             // [128]

    const int t = threadIdx.x;
    const int b = blockIdx.x;
    const float* zg = mp + (size_t)b * (NNB * CC);

    // ---- stage z: coalesced float4 burst, fused per-(k,f) L2 normalize ----
    // thread t, round j: flat float index = j*1024 + 4t. Lanes 4a..4a+3 hold
    // one contiguous 16-float (k,f) group -> 4-lane shfl_xor sum of squares.
    float4 v[16];
#pragma unroll
    for (int j = 0; j < 16; ++j) {
        const int flat = j * 1024 + 4 * t;
        v[j] = *reinterpret_cast<const float4*>(zg + flat);
    }
#pragma unroll
    for (int j = 0; j < 16; ++j) {
        float4 w = v[j];
        float s = w.x * w.x + w.y * w.y + w.z * w.z + w.w * w.w;
        s += __shfl_xor(s, 1);
        s += __shfl_xor(s, 2);
        const float inv = 1.0f / fmaxf(sqrtf(s), 1e-12f);
        w.x *= inv; w.y *= inv; w.z *= inv; w.w *= inv;
        const int flat = j * 1024 + 4 * t;
        const int k = flat >> 7;
        const int c = flat & 127;
        *reinterpret_cast<float4*>(&z_s[k * ZSTRIDE + c]) = w;
    }

    // ---- stage x: load + per-facet L2 normalize (threads 0..127) ----
    if (t < CC) {
        float xv = feat[(size_t)b * CC + t];
        float s = xv * xv;
        s += __shfl_xor(s, 1);
        s += __shfl_xor(s, 2);
        s += __shfl_xor(s, 4);
        s += __shfl_xor(s, 8);
        const float inv = 1.0f / fmaxf(sqrtf(s), 1e-12f);
        xv *= inv;
        x_s[t] = xv;
        u_s[t] = xv;   // u0 = x
    }
    __syncthreads();

    // ---- routing iterations ----
    const int k   = t & 127;          // phase1: this thread's neighbor
    const int fb  = (t >> 7) * 4;     // phase1: facet base (0 or 4)
    const int c4  = (t & 31) * 4;     // phase2: column base (0..124)
    const int kh  = t >> 5;           // phase2: k-chunk (0..7), 16 k's each
    const int f2  = c4 >> 4;          // phase2: facet of the column group

#pragma unroll
    for (int it = 0; it < 4; ++it) {
        // phase1: logits p[k, fb..fb+3] = sum_d z[k,f,d] * u[f,d]
        float acc0 = 0.f, acc1 = 0.f, acc2 = 0.f, acc3 = 0.f;
#pragma unroll
        for (int dj = 0; dj < 4; ++dj) {
            const float4 u0 = *reinterpret_cast<const float4*>(&u_s[(fb + 0) * DD + dj * 4]);
            const float4 u1 = *reinterpret_cast<const float4*>(&u_s[(fb + 1) * DD + dj * 4]);
            const float4 u2 = *reinterpret_cast<const float4*>(&u_s[(fb + 2) * DD + dj * 4]);
            const float4 u3 = *reinterpret_cast<const float4*>(&u_s[(fb + 3) * DD + dj * 4]);
            const float4 z0 = *reinterpret_cast<const float4*>(&z_s[k * ZSTRIDE + (fb + 0) * DD + dj * 4]);
            const float4 z1 = *reinterpret_cast<const float4*>(&z_s[k * ZSTRIDE + (fb + 1) * DD + dj * 4]);
            const float4 z2 = *reinterpret_cast<const float4*>(&z_s[k * ZSTRIDE + (fb + 2) * DD + dj * 4]);
            const float4 z3 = *reinterpret_cast<const float4*>(&z_s[k * ZSTRIDE + (fb + 3) * DD + dj * 4]);
            acc0 += z0.x * u0.x + z0.y * u0.y + z0.z * u0.z + z0.w * u0.w;
            acc1 += z1.x * u1.x + z1.y * u1.y + z1.z * u1.z + z1.w * u1.w;
            acc2 += z2.x * u2.x + z2.y * u2.y + z2.z * u2.z + z2.w * u2.w;
            acc3 += z3.x * u3.x + z3.y * u3.y + z3.z * u3.z + z3.w * u3.w;
        }
        p_s[k * PSTRIDE + fb + 0] = acc0;
        p_s[k * PSTRIDE + fb + 1] = acc1;
        p_s[k * PSTRIDE + fb + 2] = acc2;
        p_s[k * PSTRIDE + fb + 3] = acc3;
        __syncthreads();

        // softmax over facets (8) for this k; both half-threads compute the
        // full max/sum redundantly, each writes its own 4 weights.
        float l[8];
#pragma unroll
        for (int f = 0; f < 8; ++f) l[f] = p_s[k * PSTRIDE + f];
        float m = l[0];
#pragma unroll
        for (int f = 1; f < 8; ++f) m = fmaxf(m, l[f]);
        float e[8];
        float sum = 0.f;
#pragma unroll
        for (int f = 0; f < 8; ++f) { e[f] = __expf(l[f] - m); sum += e[f]; }
        const float isum = 1.0f / sum;
        w_s[k * PSTRIDE + fb + 0] = e[fb + 0] * isum;
        w_s[k * PSTRIDE + fb + 1] = e[fb + 1] * isum;
        w_s[k * PSTRIDE + fb + 2] = e[fb + 2] * isum;
        w_s[k * PSTRIDE + fb + 3] = e[fb + 3] * isum;
        __syncthreads();

        // phase2: partial u over this thread's 16-k chunk for 4 columns
        float4 ua = make_float4(0.f, 0.f, 0.f, 0.f);
#pragma unroll
        for (int ki = 0; ki < 16; ++ki) {
            const int kk = kh * 16 + ki;
            const float w = w_s[kk * PSTRIDE + f2];
            const float4 zv = *reinterpret_cast<const float4*>(&z_s[kk * ZSTRIDE + c4]);
            ua.x += zv.x * w; ua.y += zv.y * w; ua.z += zv.z * w; ua.w += zv.w * w;
        }
        *reinterpret_cast<float4*>(&part_s[kh * 128 + c4]) = ua;  // p_s is dead here
        __syncthreads();

        // combine partials + x; normalize (iters 0..2) or emit (iter 3)
        if (t < CC) {
            float u = x_s[t];
#pragma unroll
            for (int j = 0; j < 8; ++j) u += part_s[j * 128 + t];
            if (it < 3) {
                float s = u * u;
                s += __shfl_xor(s, 1);
                s += __shfl_xor(s, 2);
                s += __shfl_xor(s, 4);
                s += __shfl_xor(s, 8);
                const float inv = 1.0f / fmaxf(sqrtf(s), 1e-12f);
                u_s[t] = u * inv;
            } else {
                out[(size_t)b * CC + t] = u;
            }
        }
        __syncthreads();
    }
}

extern "C" void kernel_launch(void* const* d_in, const int* in_sizes, int n_in,
                              void* d_out, int out_size, void* d_ws, size_t ws_size,
                              hipStream_t stream) {
    const float* feat = (const float*)d_in[0];   // features [B,1,128] fp32
    const float* mp   = (const float*)d_in[1];   // metapath [B,1,128,128] fp32
    float* out = (float*)d_out;                  // [B,128] fp32
    const int B = in_sizes[0] / CC;              // 4096
    hete_routing_kernel<<<B, 256, 0, stream>>>(feat, mp, out);
}

// Round 2
// 81.252 us; speedup vs baseline: 1.2754x; 1.2754x over previous
//
#include <hip/hip_runtime.h>
#include <math.h>

// HeteAttention capsule routing, MI355X — register-resident z.
// B=4096, n=1, N=128 neighbors, F=8 facets, D=16, n_iter=4, C=F*D=128.
// One block (256 thr = 4 waves) per batch element b.
// Thread (kg, cg): kg = wave*4 + (lane>>4) in [0,16) owns k = kg*8..kg*8+7;
//                  cg = lane&15 owns c = cg*8..cg*8+7 (8 contiguous channels,
//                  half of facet f = cg>>1; partner lane cg^1 holds other half).
// z[8k][8c] = 64 VGPRs, lives in registers for all 4 routing iterations.
// Cross-lane: shfl_xor(1) completes facet dots; shfl_xor(2,4,8) does the
// softmax over facets; shfl_xor(16,32) reduces over kgl; a 4KB LDS buffer
// (double-buffered) does the cross-wave k-reduction. One barrier per iter.

#define CC 128
#define EPS 1e-12f

__global__ __launch_bounds__(256, 4)
void hete_routing_kernel(const float* __restrict__ feat,   // [B, 128]
                         const float* __restrict__ mp,     // [B, 128, 128]
                         float* __restrict__ out)          // [B, 128]
{
    __shared__ float part[2][4][CC];   // dbuf x wave x channel

    const int t = threadIdx.x;
    const int b = blockIdx.x;
    const int wave = t >> 6;
    const int lane = t & 63;
    const int cg = lane & 15;
    const int kgl = lane >> 4;         // 0..3
    const int kg = wave * 4 + kgl;     // 0..15
    const int c0 = cg * 8;

    const float* zg = mp + (size_t)b * (128 * CC);

    // ---- load z slice to registers ----
    float4 za0[8], za1[8];
#pragma unroll
    for (int kk = 0; kk < 8; ++kk) {
        const float* p = zg + (kg * 8 + kk) * CC + c0;
        za0[kk] = *reinterpret_cast<const float4*>(p);
        za1[kk] = *reinterpret_cast<const float4*>(p + 4);
    }
    // ---- normalize z per (k, facet): local sumsq + partner half ----
#pragma unroll
    for (int kk = 0; kk < 8; ++kk) {
        float s = za0[kk].x * za0[kk].x + za0[kk].y * za0[kk].y
                + za0[kk].z * za0[kk].z + za0[kk].w * za0[kk].w
                + za1[kk].x * za1[kk].x + za1[kk].y * za1[kk].y
                + za1[kk].z * za1[kk].z + za1[kk].w * za1[kk].w;
        s += __shfl_xor(s, 1);
        const float inv = 1.0f / fmaxf(sqrtf(s), EPS);
        za0[kk].x *= inv; za0[kk].y *= inv; za0[kk].z *= inv; za0[kk].w *= inv;
        za1[kk].x *= inv; za1[kk].y *= inv; za1[kk].z *= inv; za1[kk].w *= inv;
    }

    // ---- load + normalize x slice (redundant across kg threads; L1 broadcast) ----
    float xr[8], ur[8];
    {
        const float* p = feat + (size_t)b * CC + c0;
        const float4 a = *reinterpret_cast<const float4*>(p);
        const float4 c = *reinterpret_cast<const float4*>(p + 4);
        xr[0] = a.x; xr[1] = a.y; xr[2] = a.z; xr[3] = a.w;
        xr[4] = c.x; xr[5] = c.y; xr[6] = c.z; xr[7] = c.w;
        float s = 0.f;
#pragma unroll
        for (int j = 0; j < 8; ++j) s += xr[j] * xr[j];
        s += __shfl_xor(s, 1);
        const float inv = 1.0f / fmaxf(sqrtf(s), EPS);
#pragma unroll
        for (int j = 0; j < 8; ++j) { xr[j] *= inv; ur[j] = xr[j]; }
    }

    // ---- routing iterations ----
#pragma unroll
    for (int it = 0; it < 4; ++it) {
        // phase1: logits l[k] = z[k,f,:]·u[f,:]; softmax over facets -> w[kk]
        float w[8];
#pragma unroll
        for (int kk = 0; kk < 8; ++kk) {
            float pl = za0[kk].x * ur[0] + za0[kk].y * ur[1]
                     + za0[kk].z * ur[2] + za0[kk].w * ur[3]
                     + za1[kk].x * ur[4] + za1[kk].y * ur[5]
                     + za1[kk].z * ur[6] + za1[kk].w * ur[7];
            pl += __shfl_xor(pl, 1);       // complete the 16-d facet dot
            w[kk] = pl;
        }
#pragma unroll
        for (int kk = 0; kk < 8; ++kk) {
            float m = w[kk];
            m = fmaxf(m, __shfl_xor(m, 2));   // facet index = lane bits 1..3
            m = fmaxf(m, __shfl_xor(m, 4));
            m = fmaxf(m, __shfl_xor(m, 8));
            const float e = __expf(w[kk] - m);
            float su = e;
            su += __shfl_xor(su, 2);
            su += __shfl_xor(su, 4);
            su += __shfl_xor(su, 8);
            w[kk] = e / su;
        }

        // phase2: partial u over this thread's 8 k's, 8 channels
        float pu[8];
#pragma unroll
        for (int j = 0; j < 8; ++j) pu[j] = 0.f;
#pragma unroll
        for (int kk = 0; kk < 8; ++kk) {
            pu[0] += za0[kk].x * w[kk];
            pu[1] += za0[kk].y * w[kk];
            pu[2] += za0[kk].z * w[kk];
            pu[3] += za0[kk].w * w[kk];
            pu[4] += za1[kk].x * w[kk];
            pu[5] += za1[kk].y * w[kk];
            pu[6] += za1[kk].z * w[kk];
            pu[7] += za1[kk].w * w[kk];
        }
        // reduce over kgl within wave (lane bits 4,5)
#pragma unroll
        for (int j = 0; j < 8; ++j) {
            pu[j] += __shfl_xor(pu[j], 16);
            pu[j] += __shfl_xor(pu[j], 32);
        }
        // cross-wave reduce via tiny LDS buffer
        if (kgl == 0) {
            float* dst = &part[it & 1][wave][c0];
            *reinterpret_cast<float4*>(dst)     = make_float4(pu[0], pu[1], pu[2], pu[3]);
            *reinterpret_cast<float4*>(dst + 4) = make_float4(pu[4], pu[5], pu[6], pu[7]);
        }
        __syncthreads();

        float un[8];
#pragma unroll
        for (int j = 0; j < 8; ++j) un[j] = xr[j];
#pragma unroll
        for (int wv = 0; wv < 4; ++wv) {
            const float* src = &part[it & 1][wv][c0];
            const float4 a = *reinterpret_cast<const float4*>(src);
            const float4 c = *reinterpret_cast<const float4*>(src + 4);
            un[0] += a.x; un[1] += a.y; un[2] += a.z; un[3] += a.w;
            un[4] += c.x; un[5] += c.y; un[6] += c.z; un[7] += c.w;
        }

        if (it < 3) {
            float s = 0.f;
#pragma unroll
            for (int j = 0; j < 8; ++j) s += un[j] * un[j];
            s += __shfl_xor(s, 1);
            const float inv = 1.0f / fmaxf(sqrtf(s), EPS);
#pragma unroll
            for (int j = 0; j < 8; ++j) ur[j] = un[j] * inv;
        } else if (wave == 0 && kgl == 0) {
            float* dst = out + (size_t)b * CC + c0;
            *reinterpret_cast<float4*>(dst)     = make_float4(un[0], un[1], un[2], un[3]);
            *reinterpret_cast<float4*>(dst + 4) = make_float4(un[4], un[5], un[6], un[7]);
        }
    }
}

extern "C" void kernel_launch(void* const* d_in, const int* in_sizes, int n_in,
                              void* d_out, int out_size, void* d_ws, size_t ws_size,
                              hipStream_t stream) {
    const float* feat = (const float*)d_in[0];   // features [B,1,128] fp32
    const float* mp   = (const float*)d_in[1];   // metapath [B,1,128,128] fp32
    float* out = (float*)d_out;                  // [B,128] fp32
    const int B = in_sizes[0] / CC;              // 4096
    hete_routing_kernel<<<B, 256, 0, stream>>>(feat, mp, out);
}

// Round 3
// 53.282 us; speedup vs baseline: 1.9449x; 1.5249x over previous
//
#include <hip/hip_runtime.h>
#include <math.h>

// HeteAttention capsule routing, MI355X — register-resident z, DS-pipe-free
// reductions (DPP + permlane_swap instead of ds_swizzle shuffles).
// B=4096, n=1, N=128, F=8 facets, D=16, n_iter=4, C=F*D=128.
// One block (256 thr = 4 waves) per b.
// Lane map: cg = lane&15 owns channels c = cg*8..cg*8+7; lane bit0 = which
// half of facet f = cg>>1 (facet = lane bits 1..3); kgl = lane>>4 (bits 4,5);
// kg = wave*4+kgl owns k = kg*8..kg*8+7. z slice = 64 VGPRs.
// Reductions: bit0 -> DPP quad_perm(xor1); facet-sum bits1..3 ->
// quad_perm(xor2)+row_half_mirror+row_mirror (lower bits uniform by then);
// kgl bits4,5 -> permlane16_swap / permlane32_swap (VALU). Softmax max-pass
// dropped: logits are unit-vector dots, |l|<=1, shift-invariant.

#define CC 128

typedef unsigned u32x2 __attribute__((ext_vector_type(2)));

template<int CTRL>
__device__ __forceinline__ float dpp_add(float x) {
    int y = __builtin_amdgcn_update_dpp(0, __float_as_int(x), CTRL, 0xF, 0xF, true);
    return x + __int_as_float(y);
}
#define DPP_XOR1 0xB1   // quad_perm [1,0,3,2]
#define DPP_XOR2 0x4E   // quad_perm [2,3,0,1]
#define DPP_HMIR 0x141  // row_half_mirror (lane^7)
#define DPP_MIR  0x140  // row_mirror      (lane^15)

__device__ __forceinline__ float xor16_add(float v) {
#if __has_builtin(__builtin_amdgcn_permlane16_swap)
    u32x2 r = __builtin_amdgcn_permlane16_swap(__float_as_uint(v), __float_as_uint(v), false, false);
    return __uint_as_float(r.x) + __uint_as_float(r.y);
#else
    return v + __shfl_xor(v, 16);
#endif
}
__device__ __forceinline__ float xor32_add(float v) {
#if __has_builtin(__builtin_amdgcn_permlane32_swap)
    u32x2 r = __builtin_amdgcn_permlane32_swap(__float_as_uint(v), __float_as_uint(v), false, false);
    return __uint_as_float(r.x) + __uint_as_float(r.y);
#else
    return v + __shfl_xor(v, 32);
#endif
}

__device__ __forceinline__ float rsq_guard(float s) {
    return __builtin_amdgcn_rsqf(fmaxf(s, 1e-24f));
}

__global__ __launch_bounds__(256, 4)
void hete_routing_kernel(const float* __restrict__ feat,   // [B, 128]
                         const float* __restrict__ mp,     // [B, 128, 128]
                         float* __restrict__ out)          // [B, 128]
{
    __shared__ float part[2][4][CC];   // dbuf x wave x channel (4 KB)

    const int t = threadIdx.x;
    const int b = blockIdx.x;
    const int wave = t >> 6;
    const int lane = t & 63;
    const int cg = lane & 15;
    const int kgl = lane >> 4;         // 0..3
    const int kg = wave * 4 + kgl;     // 0..15
    const int c0 = cg * 8;

    const float* zg = mp + (size_t)b * (128 * CC);

    // ---- load z slice to registers ----
    float4 za0[8], za1[8];
#pragma unroll
    for (int kk = 0; kk < 8; ++kk) {
        const float* p = zg + (kg * 8 + kk) * CC + c0;
        za0[kk] = *reinterpret_cast<const float4*>(p);
        za1[kk] = *reinterpret_cast<const float4*>(p + 4);
    }
    // ---- normalize z per (k, facet): local sumsq + partner-lane half ----
#pragma unroll
    for (int kk = 0; kk < 8; ++kk) {
        float s = za0[kk].x * za0[kk].x + za0[kk].y * za0[kk].y
                + za0[kk].z * za0[kk].z + za0[kk].w * za0[kk].w
                + za1[kk].x * za1[kk].x + za1[kk].y * za1[kk].y
                + za1[kk].z * za1[kk].z + za1[kk].w * za1[kk].w;
        s = dpp_add<DPP_XOR1>(s);
        const float inv = rsq_guard(s);
        za0[kk].x *= inv; za0[kk].y *= inv; za0[kk].z *= inv; za0[kk].w *= inv;
        za1[kk].x *= inv; za1[kk].y *= inv; za1[kk].z *= inv; za1[kk].w *= inv;
    }

    // ---- load + normalize x slice ----
    float xr[8], ur[8];
    {
        const float* p = feat + (size_t)b * CC + c0;
        const float4 a = *reinterpret_cast<const float4*>(p);
        const float4 c = *reinterpret_cast<const float4*>(p + 4);
        xr[0] = a.x; xr[1] = a.y; xr[2] = a.z; xr[3] = a.w;
        xr[4] = c.x; xr[5] = c.y; xr[6] = c.z; xr[7] = c.w;
        float s = 0.f;
#pragma unroll
        for (int j = 0; j < 8; ++j) s += xr[j] * xr[j];
        s = dpp_add<DPP_XOR1>(s);
        const float inv = rsq_guard(s);
#pragma unroll
        for (int j = 0; j < 8; ++j) { xr[j] *= inv; ur[j] = xr[j]; }
    }

    // ---- routing iterations ----
#pragma unroll
    for (int it = 0; it < 4; ++it) {
        // phase1: logits l[k] = z[k,f,:]·u[f,:] (complete 16-d dot via xor1)
        float w[8];
#pragma unroll
        for (int kk = 0; kk < 8; ++kk) {
            float pl = za0[kk].x * ur[0] + za0[kk].y * ur[1]
                     + za0[kk].z * ur[2] + za0[kk].w * ur[3]
                     + za1[kk].x * ur[4] + za1[kk].y * ur[5]
                     + za1[kk].z * ur[6] + za1[kk].w * ur[7];
            w[kk] = dpp_add<DPP_XOR1>(pl);
        }
        // softmax over facets (lane bits 1..3), no max-shift needed (|l|<=1)
#pragma unroll
        for (int kk = 0; kk < 8; ++kk) {
            const float e = __expf(w[kk]);
            float su = dpp_add<DPP_XOR2>(e);    // sum over bit1 (uniform bit0)
            su = dpp_add<DPP_HMIR>(su);         // ^7 == ^4 given uniform 0,1
            su = dpp_add<DPP_MIR>(su);          // ^15 == ^8 given uniform 0..2
            w[kk] = e * __builtin_amdgcn_rcpf(su);
        }

        // phase2: partial u over this thread's 8 k's, 8 channels
        float pu[8];
#pragma unroll
        for (int j = 0; j < 8; ++j) pu[j] = 0.f;
#pragma unroll
        for (int kk = 0; kk < 8; ++kk) {
            pu[0] += za0[kk].x * w[kk];
            pu[1] += za0[kk].y * w[kk];
            pu[2] += za0[kk].z * w[kk];
            pu[3] += za0[kk].w * w[kk];
            pu[4] += za1[kk].x * w[kk];
            pu[5] += za1[kk].y * w[kk];
            pu[6] += za1[kk].z * w[kk];
            pu[7] += za1[kk].w * w[kk];
        }
        // reduce over kgl (lane bits 4,5) via permlane swaps (VALU)
#pragma unroll
        for (int j = 0; j < 8; ++j) {
            pu[j] = xor16_add(pu[j]);
            pu[j] = xor32_add(pu[j]);
        }
        // cross-wave reduce via tiny LDS buffer
        if (kgl == 0) {
            float* dst = &part[it & 1][wave][c0];
            *reinterpret_cast<float4*>(dst)     = make_float4(pu[0], pu[1], pu[2], pu[3]);
            *reinterpret_cast<float4*>(dst + 4) = make_float4(pu[4], pu[5], pu[6], pu[7]);
        }
        __syncthreads();

        float un[8];
#pragma unroll
        for (int j = 0; j < 8; ++j) un[j] = xr[j];
#pragma unroll
        for (int wv = 0; wv < 4; ++wv) {
            const float* src = &part[it & 1][wv][c0];
            const float4 a = *reinterpret_cast<const float4*>(src);
            const float4 c = *reinterpret_cast<const float4*>(src + 4);
            un[0] += a.x; un[1] += a.y; un[2] += a.z; un[3] += a.w;
            un[4] += c.x; un[5] += c.y; un[6] += c.z; un[7] += c.w;
        }

        if (it < 3) {
            float s = 0.f;
#pragma unroll
            for (int j = 0; j < 8; ++j) s += un[j] * un[j];
            s = dpp_add<DPP_XOR1>(s);
            const float inv = rsq_guard(s);
#pragma unroll
            for (int j = 0; j < 8; ++j) ur[j] = un[j] * inv;
        } else if (wave == 0 && kgl == 0) {
            float* dst = out + (size_t)b * CC + c0;
            *reinterpret_cast<float4*>(dst)     = make_float4(un[0], un[1], un[2], un[3]);
            *reinterpret_cast<float4*>(dst + 4) = make_float4(un[4], un[5], un[6], un[7]);
        }
    }
}

extern "C" void kernel_launch(void* const* d_in, const int* in_sizes, int n_in,
                              void* d_out, int out_size, void* d_ws, size_t ws_size,
                              hipStream_t stream) {
    const float* feat = (const float*)d_in[0];   // features [B,1,128] fp32
    const float* mp   = (const float*)d_in[1];   // metapath [B,1,128,128] fp32
    float* out = (float*)d_out;                  // [B,128] fp32
    const int B = in_sizes[0] / CC;              // 4096
    hete_routing_kernel<<<B, 256, 0, stream>>>(feat, mp, out);
}